// Round 11
// baseline (2584.774 us; speedup 1.0000x reference)
//
#include <hip/hip_runtime.h>
#include <hip/hip_bf16.h>
#include <math.h>

// dims
constexpr int B_ = 64, S_ = 512, LP_ = 18, CE_ = 10, LF_ = 32;
constexpr int WE_ = 200, H_ = 200, T_ = 64;
constexpr int N_ = B_ * S_;        // 32768 tokens, n = b*S + s = t*64 + j
constexpr int KP_ = 256;           // padded K for proj GEMM (232 -> 256)
constexpr int G4_ = 800;           // 4*H
constexpr int NG_ = 1600;          // both directions stacked
constexpr float L2E_ = 1.4426950408889634f;

typedef short short8 __attribute__((ext_vector_type(8)));
typedef float f32x4 __attribute__((ext_vector_type(4)));

__device__ __forceinline__ ushort bf16bits(float v) {
  return __bfloat16_as_ushort(__float2bfloat16(v));
}
__device__ __forceinline__ float bf2f(ushort u) {
  return __uint_as_float(((uint)u) << 16);
}
__device__ __forceinline__ float exp2fast(float x) {
  float r; asm("v_exp_f32 %0, %1" : "=v"(r) : "v"(x)); return r;
}
// sigmoid with input pre-scaled by log2e:  sig2(y) = 1/(1+2^-y)
__device__ __forceinline__ float sig2(float y) {
  return __builtin_amdgcn_rcpf(1.f + exp2fast(-y));
}

// ---------------- K1: char CNN + embeddings -> Xb [N, 256] bf16 (zero-padded) ----------------
__global__ __launch_bounds__(256) void k_build_x(
    const int* __restrict__ char_ids, const int* __restrict__ word_ids,
    const float* __restrict__ word_emb, const float* __restrict__ char_emb,
    const float* __restrict__ conv_w, const float* __restrict__ conv_b,
    ushort* __restrict__ Xb)
{
  __shared__ float ce[4][LP_ * CE_];
  const int wave = threadIdx.x >> 6, lane = threadIdx.x & 63;
  const int n = blockIdx.x * 4 + wave;

  for (int i = lane; i < LP_ * CE_; i += 64) {
    int c = char_ids[n * LP_ + i / CE_];
    ce[wave][i] = char_emb[c * CE_ + (i % CE_)];
  }
  const float* we = word_emb + (size_t)word_ids[n] * WE_;
  ushort* xr = Xb + (size_t)n * KP_;
  for (int i = lane; i < WE_; i += 64) xr[i] = bf16bits(we[i]);
  if (lane < KP_ - WE_ - LF_) xr[WE_ + LF_ + lane] = 0;   // pad cols 232..255
  __syncthreads();

  const int f = lane & 31, half = lane >> 5;
  float cw[30];
  #pragma unroll
  for (int i = 0; i < 30; ++i) cw[i] = conv_w[f * 30 + i];
  float m = -1e30f;
  for (int w = half * 8; w < half * 8 + 8; ++w) {
    float acc = 0.f;
    #pragma unroll
    for (int i = 0; i < 30; ++i) acc += ce[wave][w * CE_ + i] * cw[i];
    m = fmaxf(m, acc);
  }
  m = fmaxf(m, __shfl_xor(m, 32));
  if (half == 0) xr[WE_ + f] = bf16bits(m + conv_b[f]);
}

// ---------------- pack W_ih (both dirs) -> Wb [1600][256] bf16, biasc [1600] f32 ----------------
// Rows pre-scaled by log2e (i,f,o gates) / 2*log2e (g gate).
__global__ __launch_bounds__(64) void k_pack_w(
    const float* __restrict__ w_ih_f, const float* __restrict__ w_ih_b,
    const float* __restrict__ b_ih_f, const float* __restrict__ b_hh_f,
    const float* __restrict__ b_ih_b, const float* __restrict__ b_hh_b,
    ushort* __restrict__ Wb, float* __restrict__ biasc)
{
  const int r = blockIdx.x;  // 0..1599
  const int rl = r < G4_ ? r : r - G4_;
  const int gate = rl / 200;
  const float sc = (gate == 2) ? 2.f * L2E_ : L2E_;
  const float* src = r < G4_ ? w_ih_f + (size_t)rl * 232 : w_ih_b + (size_t)rl * 232;
  for (int c = threadIdx.x; c < KP_; c += 64)
    Wb[(size_t)r * KP_ + c] = (c < 232) ? bf16bits(src[c] * sc) : (ushort)0;
  if (threadIdx.x == 0)
    biasc[r] = sc * (r < G4_ ? (b_ih_f[rl] + b_hh_f[rl]) : (b_ih_b[rl] + b_hh_b[rl]));
}

// ---------------- K2: MFMA GEMM  Gc[n][1600] = Xb @ Wb^T + bias (bf16 out) ----------------
__global__ __launch_bounds__(256) void k_gemm_proj(
    const ushort* __restrict__ Xb, const ushort* __restrict__ Wb,
    const float* __restrict__ biasc, ushort* __restrict__ Gc)
{
  __shared__ __align__(16) char smem[65536];
  const int tid = threadIdx.x;
  const int lane = tid & 63, w = tid >> 6;
  const int wr = w >> 1, wc = w & 1;
  const int rowbase = blockIdx.y * 64, colbase = blockIdx.x * 64;

  const char* Ag = (const char*)(Xb + (size_t)rowbase * KP_);
  const char* Bg = (const char*)(Wb + (size_t)colbase * KP_);
  #pragma unroll
  for (int it = 0; it < 8; ++it) {
    int slot = it * 256 + tid;
    int row = slot >> 5, c16 = slot & 31;
    int src = row * 512 + c16 * 16;
    int dst = row * 512 + ((c16 * 16) ^ ((row & 7) << 4));
    *(short8*)(smem + dst) = *(const short8*)(Ag + src);
    *(short8*)(smem + 32768 + dst) = *(const short8*)(Bg + src);
  }
  __syncthreads();

  f32x4 acc[2][2] = {};
  #pragma unroll
  for (int kk = 0; kk < 8; ++kk) {
    const int kb = kk * 64 + (lane >> 4) * 16;
    short8 a[2], b[2];
    #pragma unroll
    for (int m = 0; m < 2; ++m) {
      int ar = wr * 32 + m * 16 + (lane & 15);
      a[m] = *(const short8*)(smem + ar * 512 + (kb ^ ((ar & 7) << 4)));
      int bc = wc * 32 + m * 16 + (lane & 15);
      b[m] = *(const short8*)(smem + 32768 + bc * 512 + (kb ^ ((bc & 7) << 4)));
    }
    #pragma unroll
    for (int m = 0; m < 2; ++m)
      #pragma unroll
      for (int n = 0; n < 2; ++n)
        acc[m][n] = __builtin_amdgcn_mfma_f32_16x16x32_bf16(a[m], b[n], acc[m][n], 0, 0, 0);
  }
  __syncthreads();

  float* Cs = (float*)smem;
  #pragma unroll
  for (int m = 0; m < 2; ++m)
    #pragma unroll
    for (int n = 0; n < 2; ++n)
      #pragma unroll
      for (int i = 0; i < 4; ++i) {
        int r = wr * 32 + m * 16 + (lane >> 4) * 4 + i;
        int c = wc * 32 + n * 16 + (lane & 15);
        Cs[r * 65 + c] = acc[m][n][i];
      }
  __syncthreads();

  const int r = tid >> 2, cg = (tid & 3) * 16;
  ushort ob[16];
  #pragma unroll
  for (int j = 0; j < 16; ++j)
    ob[j] = bf16bits(Cs[r * 65 + cg + j] + biasc[colbase + cg + j]);
  ushort* dst = Gc + (size_t)(rowbase + r) * NG_ + colbase + cg;
  *(short8*)(dst) = *(short8*)(ob);
  *(short8*)(dst + 8) = *(short8*)(ob + 8);
}

// ---------------- K3: LSTM recurrence v11 (= v10 + restored launch_bounds(512,2)) ----------------
// 16 blocks = 2 dirs x 8 chain-groups(8 chains). 512 thr = 8 waves, 2 slots/wave.
// 2 waves/SIMD declared -> 256-reg combined budget (VGPR+AGPR): weights kt0..4
// live in the register file (160 regs, compiler splits into AGPRs as needed),
// kt5 in wlds5, kt6 in wlds6 (+zero block, branch-free pad lanes).
// v6-proven skeleton: single __syncthreads per step, preacts loaded at step top
// (counted vmcnt hides ~2000cyc under MFMA), prescaled exp2 nonlin, setprio.
__global__ __launch_bounds__(512, 2) void k_lstm(
    const ushort* __restrict__ Gc,
    const float* __restrict__ w_hh_f, const float* __restrict__ w_hh_b,
    ushort* __restrict__ hf, ushort* __restrict__ hb)
{
  __shared__ ushort h_lds[2][16][232];             // 14,848 B, double-buffered h
  __shared__ __align__(16) char wlds5[65536];      // kt5: gid*1024 + lane*16
  __shared__ __align__(16) char wlds6[17408];      // kt6: gid*256 + lo*16 (hi==0); [16384,17408)=0

  const int tid = threadIdx.x;
  const int lane = tid & 63, w = tid >> 6;
  const int lo = lane & 15, hi = lane >> 4;
  const int dir = blockIdx.x >> 3, grp = blockIdx.x & 7;
  const float* Whh = dir ? w_hh_b : w_hh_f;
  ushort* hout = dir ? hb : hf;

  for (int i = tid; i < 2 * 16 * 232; i += 512) ((ushort*)h_lds)[i] = 0;
  if (tid < 256) ((uint*)(wlds6 + 16384))[tid] = 0;

  const int s0 = 2 * w, s1 = 2 * w + 1;
  const int off0 = s0 < 12 ? 12 * s0 : 144 + 16 * (s0 - 12);
  const int off1 = s1 < 12 ? 12 * s1 : 144 + 16 * (s1 - 12);
  const int rl0 = min(s0 < 12 ? 12 : 16, 200 - off0);
  const int rl1 = min(s1 < 12 ? 12 : 16, 200 - off1);
  const int offs[2] = {off0, off1};
  const int rls[2]  = {rl0, rl1};

  // ---- prologue: weights (pre-scaled by log2e / 2log2e) into regs + LDS ----
  short8 wreg[2][4][5];
  #pragma unroll
  for (int sl = 0; sl < 2; ++sl) {
    const int off = offs[sl], rl = rls[sl];
    const bool rowok = lo < rl;
    const int s = 2 * w + sl;
    #pragma unroll
    for (int g = 0; g < 4; ++g) {
      const float sc = (g == 2) ? 2.f * L2E_ : L2E_;
      const float* wr = Whh + (size_t)(g * 200 + off + lo) * 200;
      const int gid = s * 4 + g;
      #pragma unroll
      for (int kt = 0; kt < 7; ++kt) {
        const int k0 = kt * 32 + hi * 8;
        float v[8];
        if (rowok && k0 < 200) {
          float4 p0 = *(const float4*)(wr + k0);
          float4 p1 = *(const float4*)(wr + k0 + 4);
          v[0] = p0.x; v[1] = p0.y; v[2] = p0.z; v[3] = p0.w;
          v[4] = p1.x; v[5] = p1.y; v[6] = p1.z; v[7] = p1.w;
        } else {
          #pragma unroll
          for (int j = 0; j < 8; ++j) v[j] = 0.f;
        }
        short8 fr;
        #pragma unroll
        for (int j = 0; j < 8; ++j) fr[j] = (short)bf16bits(v[j] * sc);
        if (kt < 5) wreg[sl][g][kt] = fr;
        else if (kt == 5) *(short8*)(wlds5 + gid * 1024 + lane * 16) = fr;
        else if (hi == 0) *(short8*)(wlds6 + gid * 256 + lo * 16) = fr;
      }
    }
  }

  float c_[2][4] = {};

  // step-invariant addressing
  const int rowsel = lo & 7;                       // pad lanes duplicate a real row
  const int step0 = dir ? (S_ - 1) : 0;
  const ushort* gpp = Gc + (size_t)(step0 * 64 + grp * 8 + rowsel) * NG_ + dir * G4_ + hi * 4;
  ushort* hp = hout + (size_t)(step0 * 64 + grp * 8 + lo) * H_ + hi * 4;
  const ptrdiff_t gstep = (dir ? -64 : 64) * (ptrdiff_t)NG_;
  const ptrdiff_t hstep = (dir ? -64 : 64) * (ptrdiff_t)H_;

  // kt6 read offsets (zero block for hi!=0 lanes; g*256 stays inside the zero KB)
  int b6o[2];
  #pragma unroll
  for (int sl = 0; sl < 2; ++sl)
    b6o[sl] = (hi == 0) ? ((2 * w + sl) * 4 * 256 + lo * 16) : (16384 + lo * 16);

  __syncthreads();   // weights + zeroed h + zero block visible

  auto lstm_step = [&](const ushort (*HR)[232], ushort (*HW)[232]) {
    // preact loads for THIS step; consumed ~2000cyc later at nonlin (counted vmcnt)
    uint2 pre[2][4];
    #pragma unroll
    for (int sl = 0; sl < 2; ++sl)
      #pragma unroll
      for (int g = 0; g < 4; ++g)
        pre[sl][g] = *(const uint2*)(gpp + g * 200 + offs[sl]);

    // ---- MFMA phase ----
    __builtin_amdgcn_s_setprio(1);
    f32x4 acc[2][4] = {};
    const char* hrow = (const char*)HR + lo * 464 + hi * 16;
    #pragma unroll
    for (int kt = 0; kt < 7; ++kt) {
      short8 hfr = *(const short8*)(hrow + kt * 64);
      if (kt < 5) {
        #pragma unroll
        for (int sl = 0; sl < 2; ++sl)
          #pragma unroll
          for (int g = 0; g < 4; ++g)
            acc[sl][g] = __builtin_amdgcn_mfma_f32_16x16x32_bf16(
                wreg[sl][g][kt], hfr, acc[sl][g], 0, 0, 0);
      } else if (kt == 5) {
        #pragma unroll
        for (int sl = 0; sl < 2; ++sl)
          #pragma unroll
          for (int g = 0; g < 4; ++g) {
            short8 wk = *(const short8*)(wlds5 + ((2 * w + sl) * 4 + g) * 1024 + lane * 16);
            acc[sl][g] = __builtin_amdgcn_mfma_f32_16x16x32_bf16(wk, hfr, acc[sl][g], 0, 0, 0);
          }
      } else {
        #pragma unroll
        for (int sl = 0; sl < 2; ++sl)
          #pragma unroll
          for (int g = 0; g < 4; ++g) {
            short8 wk = *(const short8*)(wlds6 + b6o[sl] + g * 256);
            acc[sl][g] = __builtin_amdgcn_mfma_f32_16x16x32_bf16(wk, hfr, acc[sl][g], 0, 0, 0);
          }
      }
    }
    __builtin_amdgcn_s_setprio(0);

    // ---- nonlinearity (prescaled gates; exp2-based) ----
    #pragma unroll
    for (int sl = 0; sl < 2; ++sl) {
      const uint2 pi = pre[sl][0], pf = pre[sl][1], pg = pre[sl][2], po = pre[sl][3];
      float hv[4];
      #pragma unroll
      for (int i = 0; i < 4; ++i) {
        const uint wi = (i < 2) ? pi.x : pi.y;
        const uint wf = (i < 2) ? pf.x : pf.y;
        const uint wg = (i < 2) ? pg.x : pg.y;
        const uint wo = (i < 2) ? po.x : po.y;
        const int sh = (i & 1) * 16;
        float gi = acc[sl][0][i] + bf2f((ushort)(wi >> sh));
        float gf = acc[sl][1][i] + bf2f((ushort)(wf >> sh));
        float gg = acc[sl][2][i] + bf2f((ushort)(wg >> sh));
        float go = acc[sl][3][i] + bf2f((ushort)(wo >> sh));
        float si = sig2(gi);
        float sf = sig2(gf);
        float so = sig2(go);
        float tg = 2.f * sig2(gg) - 1.f;               // tanh (g pre-scaled by 2log2e)
        float cn = sf * c_[sl][i] + si * tg;
        c_[sl][i] = cn;
        float tc = 2.f * sig2(cn * (2.f * L2E_)) - 1.f;
        hv[i] = so * tc;
      }
      if (lo < 8 && hi * 4 < rls[sl]) {
        uint2 pk;
        pk.x = (uint)bf16bits(hv[0]) | ((uint)bf16bits(hv[1]) << 16);
        pk.y = (uint)bf16bits(hv[2]) | ((uint)bf16bits(hv[3]) << 16);
        *(uint2*)(hp + offs[sl]) = pk;                 // global, fire-and-forget
        *(uint2*)((char*)HW + lo * 464 + offs[sl] * 2 + hi * 8) = pk;
      }
    }

    __syncthreads();   // single per-step barrier
    gpp += gstep;
    hp += hstep;
  };

  for (int tt = 0; tt < S_; tt += 2) {
    lstm_step(h_lds[0], h_lds[1]);
    lstm_step(h_lds[1], h_lds[0]);
  }
}

// ---------------- K4: tag = [hf|hb](bf16) @ out_w^T + out_b ----------------
__global__ __launch_bounds__(256) void k_out(
    const ushort* __restrict__ hf, const ushort* __restrict__ hb,
    const float* __restrict__ out_w, const float* __restrict__ out_b,
    float* __restrict__ tag)
{
  const int m = threadIdx.x >> 3;
  const int tg = threadIdx.x & 7;
  const int n = blockIdx.x * 32 + m;
  const ushort* hfp = hf + (size_t)n * H_;
  const ushort* hbp = hb + (size_t)n * H_;
  float acc[8];
  #pragma unroll
  for (int q = 0; q < 8; ++q) acc[q] = out_b[tg + 8 * q];
  for (int k = 0; k < H_ / 4; ++k) {
    uint2 hv = *(const uint2*)(hfp + k * 4);
    float x0 = bf2f((ushort)hv.x), x1 = bf2f((ushort)(hv.x >> 16));
    float x2 = bf2f((ushort)hv.y), x3 = bf2f((ushort)(hv.y >> 16));
    #pragma unroll
    for (int q = 0; q < 8; ++q) {
      float4 w = ((const float4*)(out_w + (size_t)(tg + 8 * q) * 2 * H_))[k];
      acc[q] += x0 * w.x + x1 * w.y + x2 * w.z + x3 * w.w;
    }
  }
  for (int k = 0; k < H_ / 4; ++k) {
    uint2 hv = *(const uint2*)(hbp + k * 4);
    float x0 = bf2f((ushort)hv.x), x1 = bf2f((ushort)(hv.x >> 16));
    float x2 = bf2f((ushort)hv.y), x3 = bf2f((ushort)(hv.y >> 16));
    #pragma unroll
    for (int q = 0; q < 8; ++q) {
      float4 w = ((const float4*)(out_w + (size_t)(tg + 8 * q) * 2 * H_ + H_))[k];
      acc[q] += x0 * w.x + x1 * w.y + x2 * w.z + x3 * w.w;
    }
  }
  #pragma unroll
  for (int q = 0; q < 8; ++q) tag[(size_t)n * T_ + tg + 8 * q] = acc[q];
}

// ---------------- K5: log_softmax over the sequence axis (dim=1) ----------------
__global__ __launch_bounds__(256) void k_lsm(
    const float* __restrict__ tag, float* __restrict__ out)
{
  __shared__ float red[4][T_];
  __shared__ float lse[T_];
  const int b = blockIdx.x;
  const int tt = threadIdx.x & 63, ch = threadIdx.x >> 6;
  const float* tb = tag + (size_t)b * S_ * T_;

  float m = -1e30f;
  for (int s = ch * 128; s < ch * 128 + 128; ++s) m = fmaxf(m, tb[s * T_ + tt]);
  red[ch][tt] = m;
  __syncthreads();
  if (ch == 0)
    lse[tt] = fmaxf(fmaxf(red[0][tt], red[1][tt]), fmaxf(red[2][tt], red[3][tt]));
  __syncthreads();
  m = lse[tt];
  float sum = 0.f;
  for (int s = ch * 128; s < ch * 128 + 128; ++s) sum += __expf(tb[s * T_ + tt] - m);
  __syncthreads();
  red[ch][tt] = sum;
  __syncthreads();
  if (ch == 0)
    lse[tt] = m + logf(red[0][tt] + red[1][tt] + red[2][tt] + red[3][tt]);
  __syncthreads();
  const float l = lse[tt];
  float* ob = out + (size_t)b * S_ * T_;
  for (int s = ch * 128; s < ch * 128 + 128; ++s) ob[s * T_ + tt] = tb[s * T_ + tt] - l;
}

// ---------------- launch ----------------
extern "C" void kernel_launch(void* const* d_in, const int* in_sizes, int n_in,
                              void* d_out, int out_size, void* d_ws, size_t ws_size,
                              hipStream_t stream) {
  const int*   char_ids = (const int*)d_in[0];
  const int*   word_ids = (const int*)d_in[1];
  const float* word_emb = (const float*)d_in[2];
  const float* char_emb = (const float*)d_in[3];
  const float* conv_w   = (const float*)d_in[4];
  const float* conv_b   = (const float*)d_in[5];
  const float* w_ih_f   = (const float*)d_in[6];
  const float* w_hh_f   = (const float*)d_in[7];
  const float* b_ih_f   = (const float*)d_in[8];
  const float* b_hh_f   = (const float*)d_in[9];
  const float* w_ih_b   = (const float*)d_in[10];
  const float* w_hh_b   = (const float*)d_in[11];
  const float* b_ih_b   = (const float*)d_in[12];
  const float* b_hh_b   = (const float*)d_in[13];
  const float* out_w    = (const float*)d_in[14];
  const float* out_b    = (const float*)d_in[15];

  // ws layout (bytes)
  char* ws = (char*)d_ws;
  ushort* Xb    = (ushort*)(ws);                 // 16,777,216  [32768][256] bf16
  ushort* Wb    = (ushort*)(ws + 16777216);      //    819,200  [1600][256] bf16
  float*  biasc = (float*) (ws + 17596416);      //      6,400  [1600] f32
  ushort* Gc    = (ushort*)(ws + 18422016);      // 104,857,600 [32768][1600] bf16
  ushort* hf    = (ushort*)(ws + 123279616);     // 13,107,200  [32768][200] bf16
  ushort* hb    = (ushort*)(ws + 136386816);     // 13,107,200
  float*  tag   = (float*) (ws + 149494016);     //  8,388,608  -> total 157,882,624

  hipLaunchKernelGGL(k_build_x, dim3(N_ / 4), dim3(256), 0, stream,
                     char_ids, word_ids, word_emb, char_emb, conv_w, conv_b, Xb);
  hipLaunchKernelGGL(k_pack_w, dim3(NG_), dim3(64), 0, stream,
                     w_ih_f, w_ih_b, b_ih_f, b_hh_f, b_ih_b, b_hh_b, Wb, biasc);
  hipLaunchKernelGGL(k_gemm_proj, dim3(NG_ / 64, N_ / 64), dim3(256), 0, stream,
                     Xb, Wb, biasc, Gc);
  hipLaunchKernelGGL(k_lstm, dim3(16), dim3(512), 0, stream, Gc, w_hh_f, w_hh_b, hf, hb);
  hipLaunchKernelGGL(k_out, dim3(N_ / 32), dim3(256), 0, stream, hf, hb, out_w, out_b, tag);
  hipLaunchKernelGGL(k_lsm, dim3(B_), dim3(256), 0, stream, tag, (float*)d_out);
}

// Round 12
// 1565.581 us; speedup vs baseline: 1.6510x; 1.6510x over previous
//
#include <hip/hip_runtime.h>
#include <hip/hip_bf16.h>
#include <math.h>

// dims
constexpr int B_ = 64, S_ = 512, LP_ = 18, CE_ = 10, LF_ = 32;
constexpr int WE_ = 200, H_ = 200, T_ = 64;
constexpr int N_ = B_ * S_;        // 32768 tokens, n = b*S + s = t*64 + j
constexpr int KP_ = 256;           // padded K for proj GEMM (232 -> 256)
constexpr int G4_ = 800;           // 4*H
constexpr int NG_ = 1600;          // both directions stacked
constexpr float L2E_ = 1.4426950408889634f;

typedef short short8 __attribute__((ext_vector_type(8)));
typedef float f32x4 __attribute__((ext_vector_type(4)));

__device__ __forceinline__ ushort bf16bits(float v) {
  return __bfloat16_as_ushort(__float2bfloat16(v));
}
__device__ __forceinline__ float bf2f(ushort u) {
  return __uint_as_float(((uint)u) << 16);
}
__device__ __forceinline__ float exp2fast(float x) {
  float r; asm("v_exp_f32 %0, %1" : "=v"(r) : "v"(x)); return r;
}
// sigmoid with input pre-scaled by log2e:  sig2(y) = 1/(1+2^-y)
__device__ __forceinline__ float sig2(float y) {
  return __builtin_amdgcn_rcpf(1.f + exp2fast(-y));
}

// ---------------- K1: char CNN + embeddings -> Xb [N, 256] bf16 (zero-padded) ----------------
__global__ __launch_bounds__(256) void k_build_x(
    const int* __restrict__ char_ids, const int* __restrict__ word_ids,
    const float* __restrict__ word_emb, const float* __restrict__ char_emb,
    const float* __restrict__ conv_w, const float* __restrict__ conv_b,
    ushort* __restrict__ Xb)
{
  __shared__ float ce[4][LP_ * CE_];
  const int wave = threadIdx.x >> 6, lane = threadIdx.x & 63;
  const int n = blockIdx.x * 4 + wave;

  for (int i = lane; i < LP_ * CE_; i += 64) {
    int c = char_ids[n * LP_ + i / CE_];
    ce[wave][i] = char_emb[c * CE_ + (i % CE_)];
  }
  const float* we = word_emb + (size_t)word_ids[n] * WE_;
  ushort* xr = Xb + (size_t)n * KP_;
  for (int i = lane; i < WE_; i += 64) xr[i] = bf16bits(we[i]);
  if (lane < KP_ - WE_ - LF_) xr[WE_ + LF_ + lane] = 0;   // pad cols 232..255
  __syncthreads();

  const int f = lane & 31, half = lane >> 5;
  float cw[30];
  #pragma unroll
  for (int i = 0; i < 30; ++i) cw[i] = conv_w[f * 30 + i];
  float m = -1e30f;
  for (int w = half * 8; w < half * 8 + 8; ++w) {
    float acc = 0.f;
    #pragma unroll
    for (int i = 0; i < 30; ++i) acc += ce[wave][w * CE_ + i] * cw[i];
    m = fmaxf(m, acc);
  }
  m = fmaxf(m, __shfl_xor(m, 32));
  if (half == 0) xr[WE_ + f] = bf16bits(m + conv_b[f]);
}

// ---------------- pack W_ih (both dirs) -> Wb [1600][256] bf16, biasc [1600] f32 ----------------
// Rows pre-scaled by log2e (i,f,o gates) / 2*log2e (g gate).
__global__ __launch_bounds__(64) void k_pack_w(
    const float* __restrict__ w_ih_f, const float* __restrict__ w_ih_b,
    const float* __restrict__ b_ih_f, const float* __restrict__ b_hh_f,
    const float* __restrict__ b_ih_b, const float* __restrict__ b_hh_b,
    ushort* __restrict__ Wb, float* __restrict__ biasc)
{
  const int r = blockIdx.x;  // 0..1599
  const int rl = r < G4_ ? r : r - G4_;
  const int gate = rl / 200;
  const float sc = (gate == 2) ? 2.f * L2E_ : L2E_;
  const float* src = r < G4_ ? w_ih_f + (size_t)rl * 232 : w_ih_b + (size_t)rl * 232;
  for (int c = threadIdx.x; c < KP_; c += 64)
    Wb[(size_t)r * KP_ + c] = (c < 232) ? bf16bits(src[c] * sc) : (ushort)0;
  if (threadIdx.x == 0)
    biasc[r] = sc * (r < G4_ ? (b_ih_f[rl] + b_hh_f[rl]) : (b_ih_b[rl] + b_hh_b[rl]));
}

// ---------------- K2: MFMA GEMM  Gc[n][1600] = Xb @ Wb^T + bias (bf16 out) ----------------
__global__ __launch_bounds__(256) void k_gemm_proj(
    const ushort* __restrict__ Xb, const ushort* __restrict__ Wb,
    const float* __restrict__ biasc, ushort* __restrict__ Gc)
{
  __shared__ __align__(16) char smem[65536];
  const int tid = threadIdx.x;
  const int lane = tid & 63, w = tid >> 6;
  const int wr = w >> 1, wc = w & 1;
  const int rowbase = blockIdx.y * 64, colbase = blockIdx.x * 64;

  const char* Ag = (const char*)(Xb + (size_t)rowbase * KP_);
  const char* Bg = (const char*)(Wb + (size_t)colbase * KP_);
  #pragma unroll
  for (int it = 0; it < 8; ++it) {
    int slot = it * 256 + tid;
    int row = slot >> 5, c16 = slot & 31;
    int src = row * 512 + c16 * 16;
    int dst = row * 512 + ((c16 * 16) ^ ((row & 7) << 4));
    *(short8*)(smem + dst) = *(const short8*)(Ag + src);
    *(short8*)(smem + 32768 + dst) = *(const short8*)(Bg + src);
  }
  __syncthreads();

  f32x4 acc[2][2] = {};
  #pragma unroll
  for (int kk = 0; kk < 8; ++kk) {
    const int kb = kk * 64 + (lane >> 4) * 16;
    short8 a[2], b[2];
    #pragma unroll
    for (int m = 0; m < 2; ++m) {
      int ar = wr * 32 + m * 16 + (lane & 15);
      a[m] = *(const short8*)(smem + ar * 512 + (kb ^ ((ar & 7) << 4)));
      int bc = wc * 32 + m * 16 + (lane & 15);
      b[m] = *(const short8*)(smem + 32768 + bc * 512 + (kb ^ ((bc & 7) << 4)));
    }
    #pragma unroll
    for (int m = 0; m < 2; ++m)
      #pragma unroll
      for (int n = 0; n < 2; ++n)
        acc[m][n] = __builtin_amdgcn_mfma_f32_16x16x32_bf16(a[m], b[n], acc[m][n], 0, 0, 0);
  }
  __syncthreads();

  float* Cs = (float*)smem;
  #pragma unroll
  for (int m = 0; m < 2; ++m)
    #pragma unroll
    for (int n = 0; n < 2; ++n)
      #pragma unroll
      for (int i = 0; i < 4; ++i) {
        int r = wr * 32 + m * 16 + (lane >> 4) * 4 + i;
        int c = wc * 32 + n * 16 + (lane & 15);
        Cs[r * 65 + c] = acc[m][n][i];
      }
  __syncthreads();

  const int r = tid >> 2, cg = (tid & 3) * 16;
  ushort ob[16];
  #pragma unroll
  for (int j = 0; j < 16; ++j)
    ob[j] = bf16bits(Cs[r * 65 + cg + j] + biasc[colbase + cg + j]);
  ushort* dst = Gc + (size_t)(rowbase + r) * NG_ + colbase + cg;
  *(short8*)(dst) = *(short8*)(ob);
  *(short8*)(dst + 8) = *(short8*)(ob + 8);
}

// ---------------- K3: LSTM recurrence v12 (= v7 + lane-split nonlinearity) ----------------
// 16 blocks = 2 dirs x 8 chain-groups(8 real chains). 1024 thr = 16 waves (4/SIMD).
// Wave w owns ONE unit-slot. Weights kt0..3 in regs, kt4/5 in LDS, kt6 in LDS with
// zero-block. h double-buffered in LDS. Single __syncthreads per step.
// NONLIN SPLIT: lanes lo<8 handle cells i={0,1}, lanes lo>=8 handle i={2,3} of the
// same (chain=lo&7, hi) group (they hold duplicate acc/pre) -> 2 cells/thread, all
// 64 lanes useful, VALU+TRANS per wave ~halved. h writes become per-lane b32.
__global__ __launch_bounds__(1024) void k_lstm(
    const ushort* __restrict__ Gc,
    const float* __restrict__ w_hh_f, const float* __restrict__ w_hh_b,
    ushort* __restrict__ hf, ushort* __restrict__ hb)
{
  __shared__ ushort h_lds[2][16][232];                 // 14,848 B
  __shared__ __align__(16) char wlds45[2][65536];      // kt4,kt5: gid*1024 + lane*16
  __shared__ __align__(16) char wlds6[17408];          // kt6: gid*256 + lo*16 (hi==0); [16384..17408) zeros

  const int tid = threadIdx.x;
  const int lane = tid & 63, w = tid >> 6;             // w = slot, 0..15
  const int lo = lane & 15, hi = lane >> 4;
  const bool hiHalf = lo >= 8;                         // owns cells i=2,3
  const int dir = blockIdx.x >> 3, grp = blockIdx.x & 7;
  const float* Whh = dir ? w_hh_b : w_hh_f;
  ushort* hout = dir ? hb : hf;

  for (int i = tid; i < 2 * 16 * 232; i += 1024) ((ushort*)h_lds)[i] = 0;
  if (tid < 256) ((uint*)(wlds6 + 16384))[tid] = 0;

  const int s = w;
  const int off = s < 12 ? 12 * s : 144 + 16 * (s - 12);
  const int cnt = s < 12 ? 12 : 16;
  const int rl  = min(cnt, 200 - off);

  // ---- prologue: weights (pre-scaled by log2e / 2log2e) into regs + LDS ----
  short8 wreg[4][4];   // [gate][kt0..3]
  #pragma unroll
  for (int g = 0; g < 4; ++g) {
    const float sc = (g == 2) ? 2.f * L2E_ : L2E_;
    const float* wr = Whh + (size_t)(g * 200 + off + lo) * 200;
    const bool rowok = lo < rl;
    const int gid = s * 4 + g;
    #pragma unroll
    for (int kt = 0; kt < 7; ++kt) {
      const int k0 = kt * 32 + hi * 8;
      float v[8];
      if (rowok && k0 < 200) {
        float4 p0 = *(const float4*)(wr + k0);
        float4 p1 = *(const float4*)(wr + k0 + 4);
        v[0] = p0.x; v[1] = p0.y; v[2] = p0.z; v[3] = p0.w;
        v[4] = p1.x; v[5] = p1.y; v[6] = p1.z; v[7] = p1.w;
      } else {
        #pragma unroll
        for (int j = 0; j < 8; ++j) v[j] = 0.f;
      }
      short8 fr;
      #pragma unroll
      for (int j = 0; j < 8; ++j) fr[j] = (short)bf16bits(v[j] * sc);
      if (kt < 4) wreg[g][kt] = fr;
      else if (kt < 6) *(short8*)(wlds45[kt - 4] + gid * 1024 + lane * 16) = fr;
      else if (hi == 0) *(short8*)(wlds6 + gid * 256 + lo * 16) = fr;
    }
  }

  float c2_[2] = {0.f, 0.f};   // owned cells only (i0,i1 for lo<8; i2,i3 for lo>=8)

  // step-invariant addressing
  const int rowsel = lo & 7;                       // pad lanes duplicate a real row
  const int step0 = dir ? (S_ - 1) : 0;
  const ushort* gpp = Gc + (size_t)(step0 * 64 + grp * 8 + rowsel) * NG_ + dir * G4_ + off + hi * 4;
  // global h store: row = chain (lo&7), col = off + hi*4 + (hiHalf?2:0), 2 units (uint)
  ushort* sp = hout + (size_t)(step0 * 64 + grp * 8 + rowsel) * H_ + off + hi * 4 + (hiHalf ? 2 : 0);
  const ptrdiff_t gstep = (dir ? -64 : 64) * (ptrdiff_t)NG_;
  const ptrdiff_t hstep = (dir ? -64 : 64) * (ptrdiff_t)H_;
  const bool cellok = (hi * 4 < rl);               // rl is a multiple of 4 -> same for both halves
  // LDS h write offset (within HW buffer): chain row + unit*2 bytes
  const int hwoff = rowsel * 464 + off * 2 + hi * 8 + (hiHalf ? 4 : 0);

  const char* base45a = wlds45[0] + s * 4096 + lane * 16;
  const char* base45b = wlds45[1] + s * 4096 + lane * 16;
  const char* base6   = wlds6 + ((hi == 0) ? (s * 1024 + lo * 16) : (16384 + lo * 16));

  __syncthreads();   // weights + zeroed h/zero-block visible

  #pragma unroll 2
  for (int t = 0; t < S_; ++t) {
    const ushort (*HR)[232] = h_lds[t & 1];
    ushort (*HW)[232] = h_lds[(t & 1) ^ 1];

    // preact loads for this step (in flight across the MFMA phase)
    uint2 pre[4];
    #pragma unroll
    for (int g = 0; g < 4; ++g)
      pre[g] = *(const uint2*)(gpp + g * 200);

    // ---- MFMA phase ----
    __builtin_amdgcn_s_setprio(1);
    f32x4 acc[4] = {};
    const char* hrow = (const char*)HR + lo * 464 + hi * 16;
    #pragma unroll
    for (int kt = 0; kt < 7; ++kt) {
      short8 hfr = *(const short8*)(hrow + kt * 64);
      if (kt < 4) {
        #pragma unroll
        for (int g = 0; g < 4; ++g)
          acc[g] = __builtin_amdgcn_mfma_f32_16x16x32_bf16(wreg[g][kt], hfr, acc[g], 0, 0, 0);
      } else if (kt == 4) {
        #pragma unroll
        for (int g = 0; g < 4; ++g) {
          short8 wk = *(const short8*)(base45a + g * 1024);
          acc[g] = __builtin_amdgcn_mfma_f32_16x16x32_bf16(wk, hfr, acc[g], 0, 0, 0);
        }
      } else if (kt == 5) {
        #pragma unroll
        for (int g = 0; g < 4; ++g) {
          short8 wk = *(const short8*)(base45b + g * 1024);
          acc[g] = __builtin_amdgcn_mfma_f32_16x16x32_bf16(wk, hfr, acc[g], 0, 0, 0);
        }
      } else {
        #pragma unroll
        for (int g = 0; g < 4; ++g) {
          short8 wk = *(const short8*)(base6 + g * 256);
          acc[g] = __builtin_amdgcn_mfma_f32_16x16x32_bf16(wk, hfr, acc[g], 0, 0, 0);
        }
      }
    }
    __builtin_amdgcn_s_setprio(0);

    // ---- lane-split nonlinearity: 2 owned cells per thread ----
    // owned preact pair per gate (bf16 x2 in one uint)
    const uint ui = hiHalf ? pre[0].y : pre[0].x;
    const uint uf = hiHalf ? pre[1].y : pre[1].x;
    const uint ug = hiHalf ? pre[2].y : pre[2].x;
    const uint uo = hiHalf ? pre[3].y : pre[3].x;
    // owned acc values (static indices, lane-select via cndmask)
    const float aI0 = hiHalf ? acc[0][2] : acc[0][0];
    const float aI1 = hiHalf ? acc[0][3] : acc[0][1];
    const float aF0 = hiHalf ? acc[1][2] : acc[1][0];
    const float aF1 = hiHalf ? acc[1][3] : acc[1][1];
    const float aG0 = hiHalf ? acc[2][2] : acc[2][0];
    const float aG1 = hiHalf ? acc[2][3] : acc[2][1];
    const float aO0 = hiHalf ? acc[3][2] : acc[3][0];
    const float aO1 = hiHalf ? acc[3][3] : acc[3][1];

    float hv0, hv1;
    {
      float gi = aI0 + bf2f((ushort)ui);
      float gf = aF0 + bf2f((ushort)uf);
      float gg = aG0 + bf2f((ushort)ug);
      float go = aO0 + bf2f((ushort)uo);
      float cn = sig2(gf) * c2_[0] + sig2(gi) * (2.f * sig2(gg) - 1.f);
      c2_[0] = cn;
      hv0 = sig2(go) * (2.f * sig2(cn * (2.f * L2E_)) - 1.f);
    }
    {
      float gi = aI1 + bf2f((ushort)(ui >> 16));
      float gf = aF1 + bf2f((ushort)(uf >> 16));
      float gg = aG1 + bf2f((ushort)(ug >> 16));
      float go = aO1 + bf2f((ushort)(uo >> 16));
      float cn = sig2(gf) * c2_[1] + sig2(gi) * (2.f * sig2(gg) - 1.f);
      c2_[1] = cn;
      hv1 = sig2(go) * (2.f * sig2(cn * (2.f * L2E_)) - 1.f);
    }
    const uint pkw = (uint)bf16bits(hv0) | ((uint)bf16bits(hv1) << 16);
    if (cellok) {
      *(uint*)((char*)HW + hwoff) = pkw;   // LDS next-buffer (b32, all lanes useful)
    }

    __syncthreads();   // h visible; loads/stores long retired

    if (cellok) *(uint*)sp = pkw;          // global bf16 h, fire-and-forget
    sp += hstep;
    gpp += gstep;
  }
}

// ---------------- K4: tag = [hf|hb](bf16) @ out_w^T + out_b ----------------
__global__ __launch_bounds__(256) void k_out(
    const ushort* __restrict__ hf, const ushort* __restrict__ hb,
    const float* __restrict__ out_w, const float* __restrict__ out_b,
    float* __restrict__ tag)
{
  const int m = threadIdx.x >> 3;
  const int tg = threadIdx.x & 7;
  const int n = blockIdx.x * 32 + m;
  const ushort* hfp = hf + (size_t)n * H_;
  const ushort* hbp = hb + (size_t)n * H_;
  float acc[8];
  #pragma unroll
  for (int q = 0; q < 8; ++q) acc[q] = out_b[tg + 8 * q];
  for (int k = 0; k < H_ / 4; ++k) {
    uint2 hv = *(const uint2*)(hfp + k * 4);
    float x0 = bf2f((ushort)hv.x), x1 = bf2f((ushort)(hv.x >> 16));
    float x2 = bf2f((ushort)hv.y), x3 = bf2f((ushort)(hv.y >> 16));
    #pragma unroll
    for (int q = 0; q < 8; ++q) {
      float4 w = ((const float4*)(out_w + (size_t)(tg + 8 * q) * 2 * H_))[k];
      acc[q] += x0 * w.x + x1 * w.y + x2 * w.z + x3 * w.w;
    }
  }
  for (int k = 0; k < H_ / 4; ++k) {
    uint2 hv = *(const uint2*)(hbp + k * 4);
    float x0 = bf2f((ushort)hv.x), x1 = bf2f((ushort)(hv.x >> 16));
    float x2 = bf2f((ushort)hv.y), x3 = bf2f((ushort)(hv.y >> 16));
    #pragma unroll
    for (int q = 0; q < 8; ++q) {
      float4 w = ((const float4*)(out_w + (size_t)(tg + 8 * q) * 2 * H_ + H_))[k];
      acc[q] += x0 * w.x + x1 * w.y + x2 * w.z + x3 * w.w;
    }
  }
  #pragma unroll
  for (int q = 0; q < 8; ++q) tag[(size_t)n * T_ + tg + 8 * q] = acc[q];
}

// ---------------- K5: log_softmax over the sequence axis (dim=1) ----------------
__global__ __launch_bounds__(256) void k_lsm(
    const float* __restrict__ tag, float* __restrict__ out)
{
  __shared__ float red[4][T_];
  __shared__ float lse[T_];
  const int b = blockIdx.x;
  const int tt = threadIdx.x & 63, ch = threadIdx.x >> 6;
  const float* tb = tag + (size_t)b * S_ * T_;

  float m = -1e30f;
  for (int s = ch * 128; s < ch * 128 + 128; ++s) m = fmaxf(m, tb[s * T_ + tt]);
  red[ch][tt] = m;
  __syncthreads();
  if (ch == 0)
    lse[tt] = fmaxf(fmaxf(red[0][tt], red[1][tt]), fmaxf(red[2][tt], red[3][tt]));
  __syncthreads();
  m = lse[tt];
  float sum = 0.f;
  for (int s = ch * 128; s < ch * 128 + 128; ++s) sum += __expf(tb[s * T_ + tt] - m);
  __syncthreads();
  red[ch][tt] = sum;
  __syncthreads();
  if (ch == 0)
    lse[tt] = m + logf(red[0][tt] + red[1][tt] + red[2][tt] + red[3][tt]);
  __syncthreads();
  const float l = lse[tt];
  float* ob = out + (size_t)b * S_ * T_;
  for (int s = ch * 128; s < ch * 128 + 128; ++s) ob[s * T_ + tt] = tb[s * T_ + tt] - l;
}

// ---------------- launch ----------------
extern "C" void kernel_launch(void* const* d_in, const int* in_sizes, int n_in,
                              void* d_out, int out_size, void* d_ws, size_t ws_size,
                              hipStream_t stream) {
  const int*   char_ids = (const int*)d_in[0];
  const int*   word_ids = (const int*)d_in[1];
  const float* word_emb = (const float*)d_in[2];
  const float* char_emb = (const float*)d_in[3];
  const float* conv_w   = (const float*)d_in[4];
  const float* conv_b   = (const float*)d_in[5];
  const float* w_ih_f   = (const float*)d_in[6];
  const float* w_hh_f   = (const float*)d_in[7];
  const float* b_ih_f   = (const float*)d_in[8];
  const float* b_hh_f   = (const float*)d_in[9];
  const float* w_ih_b   = (const float*)d_in[10];
  const float* w_hh_b   = (const float*)d_in[11];
  const float* b_ih_b   = (const float*)d_in[12];
  const float* b_hh_b   = (const float*)d_in[13];
  const float* out_w    = (const float*)d_in[14];
  const float* out_b    = (const float*)d_in[15];

  // ws layout (bytes)
  char* ws = (char*)d_ws;
  ushort* Xb    = (ushort*)(ws);                 // 16,777,216  [32768][256] bf16
  ushort* Wb    = (ushort*)(ws + 16777216);      //    819,200  [1600][256] bf16
  float*  biasc = (float*) (ws + 17596416);      //      6,400  [1600] f32
  ushort* Gc    = (ushort*)(ws + 18422016);      // 104,857,600 [32768][1600] bf16
  ushort* hf    = (ushort*)(ws + 123279616);     // 13,107,200  [32768][200] bf16
  ushort* hb    = (ushort*)(ws + 136386816);     // 13,107,200
  float*  tag   = (float*) (ws + 149494016);     //  8,388,608  -> total 157,882,624

  hipLaunchKernelGGL(k_build_x, dim3(N_ / 4), dim3(256), 0, stream,
                     char_ids, word_ids, word_emb, char_emb, conv_w, conv_b, Xb);
  hipLaunchKernelGGL(k_pack_w, dim3(NG_), dim3(64), 0, stream,
                     w_ih_f, w_ih_b, b_ih_f, b_hh_f, b_ih_b, b_hh_b, Wb, biasc);
  hipLaunchKernelGGL(k_gemm_proj, dim3(NG_ / 64, N_ / 64), dim3(256), 0, stream,
                     Xb, Wb, biasc, Gc);
  hipLaunchKernelGGL(k_lstm, dim3(16), dim3(1024), 0, stream, Gc, w_hh_f, w_hh_b, hf, hb);
  hipLaunchKernelGGL(k_out, dim3(N_ / 32), dim3(256), 0, stream, hf, hb, out_w, out_b, tag);
  hipLaunchKernelGGL(k_lsm, dim3(B_), dim3(256), 0, stream, tag, (float*)d_out);
}